// Round 8
// baseline (193.741 us; speedup 1.0000x reference)
//
#include <hip/hip_runtime.h>
#include <hip/hip_fp16.h>
#include <stdint.h>

#define N_NODES 50000
#define N_EDGES 800000
#define DIM 64
#define BN_EPS 1e-5f
#define CAP 64          // bucket capacity; deg ~ Poisson(16), P(>=64) ~ 1e-19
#define ZERO_NODE N_NODES   // dummy src row with QV=0 -> contributes exactly 0
#define CSTRIDE 16      // counts padded: one int per 64B line (kills false sharing)

#define PROJ_TILES 782                  // ceil(50000/64)
#define PROJ_BLOCKS (PROJ_TILES * 3)    // 2346
#define SCAT_BLOCKS 391                 // ceil(800000/2048)
#define FUSED_BLOCKS (PROJ_BLOCKS + SCAT_BLOCKS)  // 2737 = 7 * 391

// ---------------------------------------------------------------------------
// Fused projection + scatter, role-split and interleaved (blockIdx%7==6 ->
// scatter). K fp32 [50000][64]. Q,V interleaved fp16: QV[node][128] halves
// (Q = halves 0..63, V = 64..127; row 50000 = zeros). Padded counters:
// counts[dst*16] -> 1 counter per 64B line, ~16 atomics/line, no sharing.
// ---------------------------------------------------------------------------
__global__ __launch_bounds__(256) void proj_scatter_kernel(
    const float* __restrict__ feat,
    const float* __restrict__ Wk, const float* __restrict__ bk,
    const float* __restrict__ Wq, const float* __restrict__ bq,
    const float* __restrict__ Wv, const float* __restrict__ bv,
    float* __restrict__ K, __half* __restrict__ QV,
    const int* __restrict__ ei, int* __restrict__ counts,
    uint16_t* __restrict__ bucket)
{
  __shared__ float sW[DIM][DIM];      // [d][j] 16 KB
  __shared__ float sf[64][DIM + 4];   // padded 17.4 KB
  __shared__ float sb[DIM];

  const int b = blockIdx.x;
  const int tid = threadIdx.x;

  if (b % 7 == 6) {
    // ---------------- scatter role ----------------
    const int sblk = b / 7;
    const int base = sblk * 2048 + tid * 8;
    if (base >= N_EDGES) return;
    if (base + 8 <= N_EDGES) {
      const int4 s0 = *(const int4*)(ei + base);
      const int4 s1 = *(const int4*)(ei + base + 4);
      const int4 d0 = *(const int4*)(ei + N_EDGES + base);
      const int4 d1 = *(const int4*)(ei + N_EDGES + base + 4);
      const int ss[8] = {s0.x, s0.y, s0.z, s0.w, s1.x, s1.y, s1.z, s1.w};
      const int dd[8] = {d0.x, d0.y, d0.z, d0.w, d1.x, d1.y, d1.z, d1.w};
      int pos[8];
#pragma unroll
      for (int i = 0; i < 8; ++i) pos[i] = atomicAdd(&counts[dd[i] * CSTRIDE], 1);
#pragma unroll
      for (int i = 0; i < 8; ++i)
        if (pos[i] < CAP) bucket[(size_t)dd[i] * CAP + pos[i]] = (uint16_t)ss[i];
    } else {
      for (int e = base; e < N_EDGES; ++e) {
        const int src = ei[e];
        const int dst = ei[N_EDGES + e];
        const int pos = atomicAdd(&counts[dst * CSTRIDE], 1);
        if (pos < CAP) bucket[(size_t)dst * CAP + pos] = (uint16_t)src;
      }
    }
    return;
  }

  // ---------------- proj role ----------------
  const int pidx = b - b / 7;          // 0..2345
  const int mat = pidx % 3;
  const int tile = pidx / 3;
  const float* __restrict__ W = (mat == 0) ? Wk : (mat == 1) ? Wq : Wv;
  const float* __restrict__ bb = (mat == 0) ? bk : (mat == 1) ? bq : bv;

  {
    const float4* w4 = (const float4*)W;
    float4* s4 = (float4*)&sW[0][0];
    for (int i = tid; i < DIM * DIM / 4; i += 256) s4[i] = w4[i];
  }
  if (tid < DIM) sb[tid] = bb[tid];

  const int node0 = tile * 64;
  for (int i = tid; i < 64 * 16; i += 256) {
    const int n = i >> 4, d4 = i & 15;
    const int gn = node0 + n;
    float4 v = make_float4(0.f, 0.f, 0.f, 0.f);
    if (gn < N_NODES) v = ((const float4*)feat)[gn * 16 + d4];
    *(float4*)&sf[n][d4 * 4] = v;
  }
  __syncthreads();

  const int t = tid & 15;
  const int g = tid >> 4;

  float4 a[4];
  const float4 bias = *(const float4*)&sb[t * 4];
#pragma unroll
  for (int m = 0; m < 4; ++m) a[m] = bias;

  const float4* sW4 = (const float4*)&sW[0][0];
  for (int d4 = 0; d4 < 16; ++d4) {
    const float4 w0 = sW4[(4 * d4 + 0) * 16 + t];
    const float4 w1 = sW4[(4 * d4 + 1) * 16 + t];
    const float4 w2 = sW4[(4 * d4 + 2) * 16 + t];
    const float4 w3 = sW4[(4 * d4 + 3) * 16 + t];
#pragma unroll
    for (int m = 0; m < 4; ++m) {
      const float4 f = *(const float4*)&sf[g + 16 * m][4 * d4];
      a[m].x += f.x * w0.x + f.y * w1.x + f.z * w2.x + f.w * w3.x;
      a[m].y += f.x * w0.y + f.y * w1.y + f.z * w2.y + f.w * w3.y;
      a[m].z += f.x * w0.z + f.y * w1.z + f.z * w2.z + f.w * w3.z;
      a[m].w += f.x * w0.w + f.y * w1.w + f.z * w2.w + f.w * w3.w;
    }
  }

  if (mat == 0) {
#pragma unroll
    for (int m = 0; m < 4; ++m) {
      const int gn = node0 + g + 16 * m;
      if (gn < N_NODES) ((float4*)K)[gn * 16 + t] = a[m];
    }
  } else {
    // QV row = 32 uint2 per node; Q at [0..15], V at [16..31]
    const int part = (mat == 1) ? 0 : 16;
#pragma unroll
    for (int m = 0; m < 4; ++m) {
      const int gn = node0 + g + 16 * m;
      if (gn <= N_NODES) {   // row N_NODES = zero pad row
        union { __half2 h[2]; uint2 u; } pk;
        pk.h[0] = __floats2half2_rn(a[m].x, a[m].y);
        pk.h[1] = __floats2half2_rn(a[m].z, a[m].w);
        if (gn == N_NODES) { pk.u.x = 0u; pk.u.y = 0u; }
        ((uint2*)QV)[gn * 32 + part + t] = pk.u;
      }
    }
  }
}

// ---------------------------------------------------------------------------
// Gather + gate + accumulate. 8 lanes/node (32 nodes/block), uint4 (16B)
// loads, QV interleaved (per-edge lines adjacent). Per 8-edge chunk: all 16
// loads hoisted before first use. Pad with ZERO_NODE (QV=0 row).
// ---------------------------------------------------------------------------
__device__ __forceinline__ void edge_acc8(float4& a0, float4& a1,
                                          const float4 k0, const float4 k1,
                                          const uint4 qu, const uint4 vu)
{
  union { uint4 u; __half2 h[4]; } q, v;
  q.u = qu; v.u = vu;
  const float2 q0 = __half22float2(q.h[0]);
  const float2 q1 = __half22float2(q.h[1]);
  const float2 q2 = __half22float2(q.h[2]);
  const float2 q3 = __half22float2(q.h[3]);
  const float2 v0 = __half22float2(v.h[0]);
  const float2 v1 = __half22float2(v.h[1]);
  const float2 v2 = __half22float2(v.h[2]);
  const float2 v3 = __half22float2(v.h[3]);
  a0.x += v0.x * __builtin_amdgcn_rcpf(1.0f + __expf(-(k0.x + q0.x)));
  a0.y += v0.y * __builtin_amdgcn_rcpf(1.0f + __expf(-(k0.y + q0.y)));
  a0.z += v1.x * __builtin_amdgcn_rcpf(1.0f + __expf(-(k0.z + q1.x)));
  a0.w += v1.y * __builtin_amdgcn_rcpf(1.0f + __expf(-(k0.w + q1.y)));
  a1.x += v2.x * __builtin_amdgcn_rcpf(1.0f + __expf(-(k1.x + q2.x)));
  a1.y += v2.y * __builtin_amdgcn_rcpf(1.0f + __expf(-(k1.y + q2.y)));
  a1.z += v3.x * __builtin_amdgcn_rcpf(1.0f + __expf(-(k1.z + q3.x)));
  a1.w += v3.y * __builtin_amdgcn_rcpf(1.0f + __expf(-(k1.w + q3.y)));
}

__global__ __launch_bounds__(256) void aggregate_kernel(
    const int* __restrict__ counts, const uint16_t* __restrict__ bucket,
    const float4* __restrict__ K4, const uint4* __restrict__ QV,
    float4* __restrict__ agg4)
{
  const int tid = threadIdx.x;
  const int row = tid >> 3;               // 0..31
  const int n = blockIdx.x * 32 + row;
  const int t = tid & 7;                  // covers cols 8t..8t+7
  if (n >= N_NODES) return;

  const float4 k0 = K4[n * 16 + 2 * t];
  const float4 k1 = K4[n * 16 + 2 * t + 1];
  int deg = counts[n * CSTRIDE];
  if (deg > CAP) deg = CAP;
  const uint16_t* bp = bucket + (size_t)n * CAP;
  float4 a0 = make_float4(0.f, 0.f, 0.f, 0.f);
  float4 a1 = make_float4(0.f, 0.f, 0.f, 0.f);

  for (int j0 = 0; j0 < deg; j0 += 8) {
    const int navail = deg - j0;
    const int s = (t < navail) ? (int)bp[j0 + t] : ZERO_NODE;

    int sA[8]; uint4 qA[8], vA[8];
#pragma unroll
    for (int i = 0; i < 8; ++i) sA[i] = __shfl(s, i, 8);
#pragma unroll
    for (int i = 0; i < 8; ++i) {
      qA[i] = QV[sA[i] * 16 + t];       // Q part: uint4 0..7
      vA[i] = QV[sA[i] * 16 + 8 + t];   // V part: uint4 8..15
    }
#pragma unroll
    for (int i = 0; i < 8; ++i) edge_acc8(a0, a1, k0, k1, qA[i], vA[i]);
  }
  agg4[n * 16 + 2 * t] = a0;
  agg4[n * 16 + 2 * t + 1] = a1;
}

// ---------------------------------------------------------------------------
// Column sums / sums-of-squares -> stats[0..63]=sum, [64..127]=sumsq
// ---------------------------------------------------------------------------
__global__ __launch_bounds__(256) void stats_kernel(
    const float* __restrict__ agg, float* __restrict__ stats)
{
  const int c = threadIdx.x & 63;
  const int r = threadIdx.x >> 6;   // 0..3
  float s = 0.0f, ss = 0.0f;
  for (int n = blockIdx.x * 4 + r; n < N_NODES; n += gridDim.x * 4) {
    const float v = agg[n * DIM + c];
    s += v; ss += v * v;
  }
  __shared__ float red[2][4][DIM];
  red[0][r][c] = s; red[1][r][c] = ss;
  __syncthreads();
  if (threadIdx.x < DIM) {
    s  = red[0][0][c] + red[0][1][c] + red[0][2][c] + red[0][3][c];
    ss = red[1][0][c] + red[1][1][c] + red[1][2][c] + red[1][3][c];
    atomicAdd(&stats[c], s);
    atomicAdd(&stats[DIM + c], ss);
  }
}

// ---------------------------------------------------------------------------
// In-place: out = relu((agg - mean) * rsqrt(var+eps) * gamma + beta)
// (reference's `+ bias` cancels inside BN: h - mean(h) = agg - mean(agg))
// ---------------------------------------------------------------------------
__global__ __launch_bounds__(256) void out_kernel(
    float* __restrict__ out, const float* __restrict__ stats,
    const float* __restrict__ gamma, const float* __restrict__ beta)
{
  const int idx = blockIdx.x * 256 + threadIdx.x;   // float4 index
  if (idx >= N_NODES * (DIM / 4)) return;
  const int t = idx & 15;
  const float4 v = ((const float4*)out)[idx];
  const float invN = 1.0f / (float)N_NODES;
  const float vin[4] = { v.x, v.y, v.z, v.w };
  float o[4];
#pragma unroll
  for (int j = 0; j < 4; ++j) {
    const int c = t * 4 + j;
    const float mean = stats[c] * invN;
    float var = stats[DIM + c] * invN - mean * mean;
    var = var < 0.0f ? 0.0f : var;
    const float scale = rsqrtf(var + BN_EPS) * gamma[c];
    const float shift = beta[c] - mean * scale;
    const float x = vin[j] * scale + shift;
    o[j] = x > 0.0f ? x : 0.0f;
  }
  float4 r; r.x = o[0]; r.y = o[1]; r.z = o[2]; r.w = o[3];
  ((float4*)out)[idx] = r;
}

extern "C" void kernel_launch(void* const* d_in, const int* in_sizes, int n_in,
                              void* d_out, int out_size, void* d_ws, size_t ws_size,
                              hipStream_t stream) {
  (void)in_sizes; (void)n_in; (void)out_size; (void)ws_size;
  const float* feat  = (const float*)d_in[0];
  const int*   ei    = (const int*)d_in[1];
  const float* Wk    = (const float*)d_in[2];
  const float* bk    = (const float*)d_in[3];
  const float* Wq    = (const float*)d_in[4];
  const float* bq    = (const float*)d_in[5];
  const float* Wv    = (const float*)d_in[6];
  const float* bv    = (const float*)d_in[7];
  // d_in[8] = bias: cancels inside batchnorm, unused.
  const float* gamma = (const float*)d_in[9];
  const float* beta  = (const float*)d_in[10];

  // byte-offset layout (all 16B-aligned):
  char* base = (char*)d_ws;
  float*    K      = (float*)base;                 // 50000x64 fp32      12.8 MB
  __half*   QV     = (__half*)(base + 12800000);   // 50001x128 fp16     12.8 MB
  float*    stats  = (float*)(base + 25600256);    // 128 fp32            512 B
  int*      counts = (int*)(base + 25600768);      // 50000x16 int (pad)  3.2 MB
  uint16_t* bucket = (uint16_t*)(base + 28800768); // 50000*64 u16        6.4 MB
  // total ≈ 35.2 MB (round-1 proved ≥51.2 MB of ws usable)

  // zero stats + padded counts (contiguous: 512 B + 3.2 MB)
  hipMemsetAsync(stats, 0, (size_t)(512 + 50000 * CSTRIDE * 4), stream);

  proj_scatter_kernel<<<FUSED_BLOCKS, 256, 0, stream>>>(
      feat, Wk, bk, Wq, bq, Wv, bv, K, QV, ei, counts, bucket);

  aggregate_kernel<<<(N_NODES + 31) / 32, 256, 0, stream>>>(
      counts, bucket, (const float4*)K, (const uint4*)QV, (float4*)d_out);

  stats_kernel<<<256, 256, 0, stream>>>((const float*)d_out, stats);

  out_kernel<<<(N_NODES * (DIM / 4) + 255) / 256, 256, 0, stream>>>(
      (float*)d_out, stats, gamma, beta);
}